// Round 12
// baseline (65.444 us; speedup 1.0000x reference)
//
#include <hip/hip_runtime.h>
#include <hip/hip_bf16.h>
#include <stdint.h>

#define B_    64
#define N_    512
#define M2    52      // M_PARAM + 2
#define MLPH  128
#define NACT  512
#define FC_IN 2204    // 512 + 512*3 + 52*3
#define NEG   0.2f
#define NW    16      // mask words per target (512/32)

__device__ __forceinline__ float lrelu(float v){ return v > 0.f ? v : NEG * v; }

// ---------------- Kernel 1: adj -> bitmask + GAT layer 1 + transform 2 ----------------
// Grid: (8 j-tiles, 64 b), 512 threads. (proven since R3)
__global__ __launch_bounds__(512) void kfuse1(const float* __restrict__ adj,
                                              const float* __restrict__ x,
                                              const float* __restrict__ W1,
                                              const float* __restrict__ as1,
                                              const float* __restrict__ ad1,
                                              const float* __restrict__ b1,
                                              const float* __restrict__ W2,
                                              const float* __restrict__ as2,
                                              uint32_t* __restrict__ maskT,
                                              float* __restrict__ node2){
  __shared__ uint32_t lm[2][64][16];   // 8 KB
  __shared__ float node[N_][8];        // 16 KB
  int b  = blockIdx.y;
  int j0 = blockIdx.x * 64;
  int t  = threadIdx.x;

  {
    int j4 = t & 15;
    int w  = (t >> 4) & 15;
    int kh = t >> 8;
    const float* basef = adj + ((size_t)(b * N_ + (w << 5) + (kh << 4))) * N_ + (j0 + (j4 << 2));
    uint32_t m0 = 0, m1 = 0, m2 = 0, m3 = 0;
#pragma unroll
    for (int k = 0; k < 16; ++k) {
      float4 v = *(const float4*)(basef + (size_t)k * N_);
      m0 |= (v.x > 0.f ? 1u : 0u) << k;
      m1 |= (v.y > 0.f ? 1u : 0u) << k;
      m2 |= (v.z > 0.f ? 1u : 0u) << k;
      m3 |= (v.w > 0.f ? 1u : 0u) << k;
    }
    int sh = kh << 4;
    lm[kh][(j4 << 2) + 0][w] = m0 << sh;
    lm[kh][(j4 << 2) + 1][w] = m1 << sh;
    lm[kh][(j4 << 2) + 2][w] = m2 << sh;
    lm[kh][(j4 << 2) + 3][w] = m3 << sh;
  }

  {
    float xv0 = x[((size_t)(b * N_ + t)) * 3 + 0];
    float xv1 = x[((size_t)(b * N_ + t)) * 3 + 1];
    float xv2 = x[((size_t)(b * N_ + t)) * 3 + 2];
    float h[6];
#pragma unroll
    for (int c = 0; c < 6; ++c) h[c] = xv0 * W1[c] + xv1 * W1[6 + c] + xv2 * W1[12 + c];
#pragma unroll
    for (int c = 0; c < 6; ++c) node[t][c] = h[c];
    node[t][6] = h[0] * as1[0] + h[1] * as1[1] + h[2] * as1[2];
    node[t][7] = h[3] * as1[3] + h[4] * as1[4] + h[5] * as1[5];
  }
  __syncthreads();

  int w  = t & 15;
  int tg = t >> 4;
  float ad10 = ad1[0], ad11 = ad1[1], ad12 = ad1[2];
  float ad13 = ad1[3], ad14 = ad1[4], ad15 = ad1[5];
  float b10 = b1[0], b11 = b1[1], b12 = b1[2], b13 = b1[3], b14 = b1[4], b15 = b1[5];
  float as20 = as2[0], as21 = as2[1], as22 = as2[2];

#pragma unroll
  for (int p = 0; p < 2; ++p) {
    int jj = tg + p * 32;
    int j  = j0 + jj;
    uint32_t bits = lm[0][jj][w] | lm[1][jj][w];
    maskT[((size_t)(b * N_ + j)) * NW + w] = bits;
    if ((j >> 5) == w) bits |= 1u << (j & 31);

    float ed0 = node[j][0] * ad10 + node[j][1] * ad11 + node[j][2] * ad12;
    float ed1 = node[j][3] * ad13 + node[j][4] * ad14 + node[j][5] * ad15;

    float den0 = 0.f, den1 = 0.f;
    float a0 = 0.f, a1 = 0.f, a2 = 0.f, a3 = 0.f, a4 = 0.f, a5 = 0.f;
    while (bits) {
      int k = __ffs(bits) - 1;
      bits &= bits - 1;
      int i = (w << 5) + k;
      float e0 = __expf(lrelu(node[i][6] + ed0));
      float e1 = __expf(lrelu(node[i][7] + ed1));
      den0 += e0; den1 += e1;
      a0 += e0 * node[i][0]; a1 += e0 * node[i][1]; a2 += e0 * node[i][2];
      a3 += e1 * node[i][3]; a4 += e1 * node[i][4]; a5 += e1 * node[i][5];
    }
#pragma unroll
    for (int m = 1; m < 16; m <<= 1) {
      den0 += __shfl_xor(den0, m); den1 += __shfl_xor(den1, m);
      a0 += __shfl_xor(a0, m); a1 += __shfl_xor(a1, m); a2 += __shfl_xor(a2, m);
      a3 += __shfl_xor(a3, m); a4 += __shfl_xor(a4, m); a5 += __shfl_xor(a5, m);
    }
    float r0 = 1.f / den0, r1 = 1.f / den1;
    float g0 = fmaxf(a0 * r0 + b10, 0.f);
    float g1v = fmaxf(a1 * r0 + b11, 0.f);
    float g2v = fmaxf(a2 * r0 + b12, 0.f);
    float g3 = fmaxf(a3 * r1 + b13, 0.f);
    float g4 = fmaxf(a4 * r1 + b14, 0.f);
    float g5 = fmaxf(a5 * r1 + b15, 0.f);
    float h20 = g0*W2[0] + g1v*W2[3] + g2v*W2[6] + g3*W2[9]  + g4*W2[12] + g5*W2[15];
    float h21 = g0*W2[1] + g1v*W2[4] + g2v*W2[7] + g3*W2[10] + g4*W2[13] + g5*W2[16];
    float h22 = g0*W2[2] + g1v*W2[5] + g2v*W2[8] + g3*W2[11] + g4*W2[14] + g5*W2[17];
    float es2 = h20 * as20 + h21 * as21 + h22 * as22;
    if (w < 4) {
      float outv = (w == 0) ? h20 : (w == 1) ? h21 : (w == 2) ? h22 : es2;
      node2[((size_t)(b * N_ + j)) * 4 + w] = outv;
    }
  }
}

// ---------------- Kernel 2: full back half, redundant compute, no cross-block deps ----
// Grid: (4 out-quarters, 64 b) = 256 blocks, 256 threads.
// Each block: stage node2[b]+maskT[b]+idx/y -> agg ALL 512 targets (4x redundant)
// -> feat in LDS -> full MLP1 (hid, 4x redundant) -> MLP2 for its 128-output quarter.
__global__ __launch_bounds__(256) void kback3(const float* __restrict__ idx,
                                              const float* __restrict__ y,
                                              const float* __restrict__ node2,
                                              const float* __restrict__ ad2,
                                              const float* __restrict__ b2,
                                              const uint32_t* __restrict__ maskT,
                                              const float* __restrict__ Wf1,
                                              const float* __restrict__ bf1,
                                              const float* __restrict__ Wf2,
                                              const float* __restrict__ bf2,
                                              float* __restrict__ out){
  __shared__ uint32_t smask[N_][NW];   // 32 KB
  __shared__ float sn[N_][4];          // 8 KB
  __shared__ float feat[2208];         // 8.8 KB
  __shared__ float red[8][128];        // 4 KB (MLP1 reduce; reused as red2 in MLP2)
  __shared__ float hid[MLPH];          // 0.5 KB
  int q = blockIdx.x, b = blockIdx.y, t = threadIdx.x;

  // ---- stage: 8 u4 (mask) + 2 f4 (node2) + idx + y, all independent loads ----
  {
    const uint4* msrc = (const uint4*)(maskT + (size_t)b * N_ * NW);
    uint4* mdst = (uint4*)smask;
#pragma unroll
    for (int r = 0; r < 8; ++r) mdst[t + r * 256] = msrc[t + r * 256];
    const float4* nsrc = (const float4*)(node2 + (size_t)b * N_ * 4);
    float4 n0 = nsrc[t];
    float4 n1 = nsrc[t + 256];
    sn[t][0] = n0.x; sn[t][1] = n0.y; sn[t][2] = n0.z; sn[t][3] = n0.w;
    sn[t + 256][0] = n1.x; sn[t + 256][1] = n1.y; sn[t + 256][2] = n1.z; sn[t + 256][3] = n1.w;
    feat[t] = idx[(size_t)b * N_ + t];
    feat[t + 256] = idx[(size_t)b * N_ + t + 256];
    if (t < M2 * 3) feat[2048 + t] = y[(size_t)b * (M2 * 3) + t];
  }
  __syncthreads();

  // ---- aggregate all 512 targets: 16 groups x 16 lanes, 32 rounds ----
  {
    int w = t & 15, grp = t >> 4;
    float ad20 = ad2[0], ad21 = ad2[1], ad22 = ad2[2];
    float b20 = b2[0], b21 = b2[1], b22 = b2[2];
#pragma unroll 4
    for (int r = 0; r < 32; ++r) {
      int j = r * 16 + grp;
      uint32_t bits = smask[j][w];
      if ((j >> 5) == w) bits |= 1u << (j & 31);
      float ed = sn[j][0] * ad20 + sn[j][1] * ad21 + sn[j][2] * ad22;
      float den = 0.f, a0 = 0.f, a1 = 0.f, a2 = 0.f;
      while (bits) {
        int k = __ffs(bits) - 1;
        bits &= bits - 1;
        int i = (w << 5) + k;
        float e = __expf(lrelu(sn[i][3] + ed));
        den += e;
        a0 += e * sn[i][0]; a1 += e * sn[i][1]; a2 += e * sn[i][2];
      }
#pragma unroll
      for (int m = 1; m < 16; m <<= 1) {
        den += __shfl_xor(den, m);
        a0 += __shfl_xor(a0, m); a1 += __shfl_xor(a1, m); a2 += __shfl_xor(a2, m);
      }
      if (w < 3) {
        float rinv = 1.f / den;
        feat[N_ + 3 * j + w] = (w == 0 ? a0 : w == 1 ? a1 : a2) * rinv
                             + (w == 0 ? b20 : w == 1 ? b21 : b22);
      }
    }
  }
  __syncthreads();

  // ---- full MLP layer 1: thread (kq 0..7, ug 0..31), 276 k each ----
  {
    int kq = t >> 5, ug = t & 31;
    int kstart = kq * 276;
    int klen = min(276, FC_IN - kstart);   // kq=7: 272
    const float4* W4 = (const float4*)Wf1;
    float a0 = 0.f, a1 = 0.f, a2 = 0.f, a3 = 0.f;
#pragma unroll 4
    for (int k2 = 0; k2 < klen; ++k2) {
      float fv = feat[kstart + k2];                       // wave broadcast
      float4 w = W4[(size_t)(kstart + k2) * 32 + ug];     // row stride 128 floats
      a0 += fv * w.x; a1 += fv * w.y; a2 += fv * w.z; a3 += fv * w.w;
    }
    *(float4*)&red[kq][ug * 4] = make_float4(a0, a1, a2, a3);
  }
  __syncthreads();
  if (t < MLPH) {
    float s = bf1[t];
#pragma unroll
    for (int r = 0; r < 8; ++r) s += red[r][t];
    hid[t] = fmaxf(s, 0.f);
  }
  __syncthreads();

  // ---- MLP layer 2, output quarter q: thread (kh 0..7, og 0..31) ----
  {
    int kh = t >> 5, og = t & 31;
    const float4* W4 = (const float4*)Wf2;
    float a0 = 0.f, a1 = 0.f, a2 = 0.f, a3 = 0.f;
#pragma unroll
    for (int k2 = 0; k2 < 16; ++k2) {
      int kk = kh * 16 + k2;
      float hv = hid[kk];
      float4 w = W4[(size_t)kk * 128 + q * 32 + og];      // row stride 512 floats
      a0 += hv * w.x; a1 += hv * w.y; a2 += hv * w.z; a3 += hv * w.w;
    }
    __syncthreads();                                      // red reuse barrier
    *(float4*)&red[kh][og * 4] = make_float4(a0, a1, a2, a3);
  }
  __syncthreads();
  if (t < 128) {
    float s = bf2[q * 128 + t];
#pragma unroll
    for (int r = 0; r < 8; ++r) s += red[r][t];
    out[(size_t)b * NACT + q * 128 + t] = s;
  }
}

extern "C" void kernel_launch(void* const* d_in, const int* in_sizes, int n_in,
                              void* d_out, int out_size, void* d_ws, size_t ws_size,
                              hipStream_t stream) {
  const float* idx = (const float*)d_in[0];
  const float* x   = (const float*)d_in[1];
  const float* y   = (const float*)d_in[2];
  const float* adj = (const float*)d_in[3];
  const float* W1  = (const float*)d_in[4];
  const float* as1 = (const float*)d_in[5];
  const float* ad1 = (const float*)d_in[6];
  const float* b1  = (const float*)d_in[7];
  const float* W2  = (const float*)d_in[8];
  const float* as2 = (const float*)d_in[9];
  const float* ad2 = (const float*)d_in[10];
  const float* b2  = (const float*)d_in[11];
  const float* Wf1 = (const float*)d_in[12];
  const float* bf1 = (const float*)d_in[13];
  const float* Wf2 = (const float*)d_in[14];
  const float* bf2 = (const float*)d_in[15];
  float* out = (float*)d_out;

  uint8_t* ws = (uint8_t*)d_ws;
  uint32_t* maskT = (uint32_t*)ws;            // 2 MB
  float* node2    = (float*)(ws + 2097152);   // 512 KB

  hipLaunchKernelGGL(kfuse1, dim3(8, B_), dim3(512), 0, stream,
                     adj, x, W1, as1, ad1, b1, W2, as2, maskT, node2);
  hipLaunchKernelGGL(kback3, dim3(4, B_), dim3(256), 0, stream,
                     idx, y, node2, ad2, b2, maskT, Wf1, bf1, Wf2, bf2, out);
}

// Round 13
// 30.948 us; speedup vs baseline: 2.1147x; 2.1147x over previous
//
#include <hip/hip_runtime.h>
#include <hip/hip_bf16.h>
#include <stdint.h>

#define B_    64
#define N_    512
#define M2    52      // M_PARAM + 2
#define MLPH  128
#define NACT  512
#define FC_IN 2204    // 512 + 512*3 + 52*3
#define NCH   18      // feat k-chunks of 128
#define NEG   0.2f
#define NW    16      // mask words per target (512/32)

__device__ __forceinline__ float lrelu(float v){ return v > 0.f ? v : NEG * v; }

// ---------------- Kernel 1: adj -> bitmask + GAT layer 1 + transform 2 ----------------
// Grid: (8 j-tiles, 64 b), 512 threads. (proven since R3)
__global__ __launch_bounds__(512) void kfuse1(const float* __restrict__ adj,
                                              const float* __restrict__ x,
                                              const float* __restrict__ W1,
                                              const float* __restrict__ as1,
                                              const float* __restrict__ ad1,
                                              const float* __restrict__ b1,
                                              const float* __restrict__ W2,
                                              const float* __restrict__ as2,
                                              uint32_t* __restrict__ maskT,
                                              float* __restrict__ node2){
  __shared__ uint32_t lm[2][64][16];   // 8 KB
  __shared__ float node[N_][8];        // 16 KB
  int b  = blockIdx.y;
  int j0 = blockIdx.x * 64;
  int t  = threadIdx.x;

  {
    int j4 = t & 15;
    int w  = (t >> 4) & 15;
    int kh = t >> 8;
    const float* basef = adj + ((size_t)(b * N_ + (w << 5) + (kh << 4))) * N_ + (j0 + (j4 << 2));
    uint32_t m0 = 0, m1 = 0, m2 = 0, m3 = 0;
#pragma unroll
    for (int k = 0; k < 16; ++k) {
      float4 v = *(const float4*)(basef + (size_t)k * N_);
      m0 |= (v.x > 0.f ? 1u : 0u) << k;
      m1 |= (v.y > 0.f ? 1u : 0u) << k;
      m2 |= (v.z > 0.f ? 1u : 0u) << k;
      m3 |= (v.w > 0.f ? 1u : 0u) << k;
    }
    int sh = kh << 4;
    lm[kh][(j4 << 2) + 0][w] = m0 << sh;
    lm[kh][(j4 << 2) + 1][w] = m1 << sh;
    lm[kh][(j4 << 2) + 2][w] = m2 << sh;
    lm[kh][(j4 << 2) + 3][w] = m3 << sh;
  }

  {
    float xv0 = x[((size_t)(b * N_ + t)) * 3 + 0];
    float xv1 = x[((size_t)(b * N_ + t)) * 3 + 1];
    float xv2 = x[((size_t)(b * N_ + t)) * 3 + 2];
    float h[6];
#pragma unroll
    for (int c = 0; c < 6; ++c) h[c] = xv0 * W1[c] + xv1 * W1[6 + c] + xv2 * W1[12 + c];
#pragma unroll
    for (int c = 0; c < 6; ++c) node[t][c] = h[c];
    node[t][6] = h[0] * as1[0] + h[1] * as1[1] + h[2] * as1[2];
    node[t][7] = h[3] * as1[3] + h[4] * as1[4] + h[5] * as1[5];
  }
  __syncthreads();

  int w  = t & 15;
  int tg = t >> 4;
  float ad10 = ad1[0], ad11 = ad1[1], ad12 = ad1[2];
  float ad13 = ad1[3], ad14 = ad1[4], ad15 = ad1[5];
  float b10 = b1[0], b11 = b1[1], b12 = b1[2], b13 = b1[3], b14 = b1[4], b15 = b1[5];
  float as20 = as2[0], as21 = as2[1], as22 = as2[2];

#pragma unroll
  for (int p = 0; p < 2; ++p) {
    int jj = tg + p * 32;
    int j  = j0 + jj;
    uint32_t bits = lm[0][jj][w] | lm[1][jj][w];
    maskT[((size_t)(b * N_ + j)) * NW + w] = bits;
    if ((j >> 5) == w) bits |= 1u << (j & 31);

    float ed0 = node[j][0] * ad10 + node[j][1] * ad11 + node[j][2] * ad12;
    float ed1 = node[j][3] * ad13 + node[j][4] * ad14 + node[j][5] * ad15;

    float den0 = 0.f, den1 = 0.f;
    float a0 = 0.f, a1 = 0.f, a2 = 0.f, a3 = 0.f, a4 = 0.f, a5 = 0.f;
    while (bits) {
      int k = __ffs(bits) - 1;
      bits &= bits - 1;
      int i = (w << 5) + k;
      float e0 = __expf(lrelu(node[i][6] + ed0));
      float e1 = __expf(lrelu(node[i][7] + ed1));
      den0 += e0; den1 += e1;
      a0 += e0 * node[i][0]; a1 += e0 * node[i][1]; a2 += e0 * node[i][2];
      a3 += e1 * node[i][3]; a4 += e1 * node[i][4]; a5 += e1 * node[i][5];
    }
#pragma unroll
    for (int m = 1; m < 16; m <<= 1) {
      den0 += __shfl_xor(den0, m); den1 += __shfl_xor(den1, m);
      a0 += __shfl_xor(a0, m); a1 += __shfl_xor(a1, m); a2 += __shfl_xor(a2, m);
      a3 += __shfl_xor(a3, m); a4 += __shfl_xor(a4, m); a5 += __shfl_xor(a5, m);
    }
    float r0 = 1.f / den0, r1 = 1.f / den1;
    float g0 = fmaxf(a0 * r0 + b10, 0.f);
    float g1v = fmaxf(a1 * r0 + b11, 0.f);
    float g2v = fmaxf(a2 * r0 + b12, 0.f);
    float g3 = fmaxf(a3 * r1 + b13, 0.f);
    float g4 = fmaxf(a4 * r1 + b14, 0.f);
    float g5 = fmaxf(a5 * r1 + b15, 0.f);
    float h20 = g0*W2[0] + g1v*W2[3] + g2v*W2[6] + g3*W2[9]  + g4*W2[12] + g5*W2[15];
    float h21 = g0*W2[1] + g1v*W2[4] + g2v*W2[7] + g3*W2[10] + g4*W2[13] + g5*W2[16];
    float h22 = g0*W2[2] + g1v*W2[5] + g2v*W2[8] + g3*W2[11] + g4*W2[14] + g5*W2[17];
    float es2 = h20 * as20 + h21 * as21 + h22 * as22;
    if (w < 4) {
      float outv = (w == 0) ? h20 : (w == 1) ? h21 : (w == 2) ? h22 : es2;
      node2[((size_t)(b * N_ + j)) * 4 + w] = outv;
    }
  }
}

// ---------------- Kernel 2: in-chunk GAT-2 agg + MLP1 partials, Wf1 prefetch ----------
// Grid: (18 chunks, 64 b), 256 threads.
__global__ __launch_bounds__(256) void kmid(const float* __restrict__ idx,
                                            const float* __restrict__ y,
                                            const float* __restrict__ node2,
                                            const float* __restrict__ ad2,
                                            const float* __restrict__ b2,
                                            const uint32_t* __restrict__ maskT,
                                            const float* __restrict__ Wf1,
                                            float* __restrict__ partial){
  __shared__ float sn[N_][4];          // 8 KB
  __shared__ uint32_t smq[44][NW];     // 2.75 KB
  __shared__ float gloc[44][3];
  __shared__ float fs[128];
  __shared__ float pr[8][128];         // 4 KB
  int c = blockIdx.x, b = blockIdx.y, t = threadIdx.x;

  // ---- prefetch first 8 Wf1 rows for this thread's MAC tile (overlaps staging+agg) ----
  int kq = t >> 5, ug = t & 31;
  const float4* wrow = (const float4*)(Wf1 + ((size_t)(c * 128 + kq * 16)) * MLPH) + ug;
  float4 wr0, wr1, wr2, wr3, wr4, wr5, wr6, wr7;
  if (c < 17) {
    wr0 = wrow[0 * 32]; wr1 = wrow[1 * 32]; wr2 = wrow[2 * 32]; wr3 = wrow[3 * 32];
    wr4 = wrow[4 * 32]; wr5 = wrow[5 * 32]; wr6 = wrow[6 * 32]; wr7 = wrow[7 * 32];
  }

  if (c >= 4 && c < 16) {
    int kg0 = c * 128 - 512;
    int j0n = kg0 / 3;
    int j1n = (kg0 + 127) / 3;
    int nrow = j1n - j0n + 1;          // <= 44
    const float4* nsrc = (const float4*)(node2 + (size_t)b * N_ * 4);
    const uint4*  msrc = (const uint4*)(maskT + ((size_t)b * N_ + j0n) * NW);
    float4 n0 = nsrc[t];
    float4 n1 = nsrc[t + 256];
    uint4 mv = make_uint4(0u, 0u, 0u, 0u);
    if (t < nrow * 4) mv = msrc[t];
    sn[t][0] = n0.x; sn[t][1] = n0.y; sn[t][2] = n0.z; sn[t][3] = n0.w;
    sn[t + 256][0] = n1.x; sn[t + 256][1] = n1.y; sn[t + 256][2] = n1.z; sn[t + 256][3] = n1.w;
    if (t < nrow * 4) ((uint4*)smq)[t] = mv;
    __syncthreads();

    int w = t & 15, grp = t >> 4;
    float ad20 = ad2[0], ad21 = ad2[1], ad22 = ad2[2];
    float b20 = b2[0], b21 = b2[1], b22 = b2[2];
#pragma unroll
    for (int rr = 0; rr < 3; ++rr) {
      int ji = grp + rr * 16;
      if (ji < nrow) {
        int j = j0n + ji;
        uint32_t bits = smq[ji][w];
        if ((j >> 5) == w) bits |= 1u << (j & 31);
        float ed = sn[j][0] * ad20 + sn[j][1] * ad21 + sn[j][2] * ad22;
        float den = 0.f, a0 = 0.f, a1 = 0.f, a2 = 0.f;
        while (bits) {
          int k = __ffs(bits) - 1;
          bits &= bits - 1;
          int i = (w << 5) + k;
          float e = __expf(lrelu(sn[i][3] + ed));
          den += e;
          a0 += e * sn[i][0]; a1 += e * sn[i][1]; a2 += e * sn[i][2];
        }
#pragma unroll
        for (int m = 1; m < 16; m <<= 1) {
          den += __shfl_xor(den, m);
          a0 += __shfl_xor(a0, m); a1 += __shfl_xor(a1, m); a2 += __shfl_xor(a2, m);
        }
        if (w < 3) {
          float rinv = 1.f / den;
          gloc[ji][w] = (w == 0 ? a0 : w == 1 ? a1 : a2) * rinv
                      + (w == 0 ? b20 : w == 1 ? b21 : b22);
        }
      }
    }
    __syncthreads();
    if (t < 128) {
      int kg = kg0 + t;
      int j = kg / 3, comp = kg - 3 * j;
      fs[t] = gloc[j - j0n][comp];
    }
  } else {
    if (t < 128) {
      int k = c * 128 + t;
      float v = 0.f;
      if (k < N_)                      v = idx[(size_t)b * N_ + k];
      else if (k >= 2048 && k < FC_IN) v = y[(size_t)b * (M2 * 3) + (k - 2048)];
      fs[t] = v;
    }
  }
  __syncthreads();

  // ---- MLP layer 1 partials: first 8 k from prefetched regs, last 8 in-loop ----
  {
    float a0 = 0.f, a1 = 0.f, a2 = 0.f, a3 = 0.f;
    if (c < 17) {
      float f0 = fs[kq * 16 + 0], f1 = fs[kq * 16 + 1], f2 = fs[kq * 16 + 2], f3 = fs[kq * 16 + 3];
      float f4 = fs[kq * 16 + 4], f5 = fs[kq * 16 + 5], f6 = fs[kq * 16 + 6], f7 = fs[kq * 16 + 7];
      a0 = f0*wr0.x + f1*wr1.x + f2*wr2.x + f3*wr3.x + f4*wr4.x + f5*wr5.x + f6*wr6.x + f7*wr7.x;
      a1 = f0*wr0.y + f1*wr1.y + f2*wr2.y + f3*wr3.y + f4*wr4.y + f5*wr5.y + f6*wr6.y + f7*wr7.y;
      a2 = f0*wr0.z + f1*wr1.z + f2*wr2.z + f3*wr3.z + f4*wr4.z + f5*wr5.z + f6*wr6.z + f7*wr7.z;
      a3 = f0*wr0.w + f1*wr1.w + f2*wr2.w + f3*wr3.w + f4*wr4.w + f5*wr5.w + f6*wr6.w + f7*wr7.w;
#pragma unroll
      for (int k2 = 8; k2 < 16; ++k2) {
        float fv = fs[kq * 16 + k2];
        float4 w = wrow[k2 * 32];
        a0 += fv * w.x; a1 += fv * w.y; a2 += fv * w.z; a3 += fv * w.w;
      }
    } else {
      int kend = min(16, (FC_IN - 17 * 128) - kq * 16);   // kq=0:16, kq=1:12, else <=0
      for (int k2 = 0; k2 < kend; ++k2) {
        float fv = fs[kq * 16 + k2];
        float4 w = wrow[k2 * 32];
        a0 += fv * w.x; a1 += fv * w.y; a2 += fv * w.z; a3 += fv * w.w;
      }
    }
    *(float4*)&pr[kq][ug * 4] = make_float4(a0, a1, a2, a3);
  }
  __syncthreads();
  if (t < 128) {
    float s = 0.f;
#pragma unroll
    for (int q = 0; q < 8; ++q) s += pr[q][t];
    partial[((size_t)b * NCH + c) * MLPH + t] = s;
  }
}

// ---------------- Kernel 3: reduce + relu + MLP layer 2, widened ----------------
// Grid: (16 out-groups of 32, 64 b) = 1024 blocks, 256 threads.
// Thread (kg 0..31, oc 0..7): 4-deep k, Wf2 prefetched before partial staging.
__global__ __launch_bounds__(256) void kmlp2w(const float* __restrict__ partial,
                                              const float* __restrict__ bf1,
                                              const float* __restrict__ Wf2,
                                              const float* __restrict__ bf2,
                                              float* __restrict__ out){
  __shared__ float part[NCH * MLPH];   // 9 KB
  __shared__ float hid[MLPH];
  __shared__ float red[32][32];        // 4 KB
  int q = blockIdx.x, b = blockIdx.y, t = threadIdx.x;
  int oc = t & 7, kg = t >> 3;

  // prefetch Wf2 (overlaps partial staging)
  const float4* W4 = (const float4*)Wf2;
  size_t col = (size_t)(q * 8 + oc);
  float4 w0 = W4[(size_t)(kg * 4 + 0) * 128 + col];
  float4 w1 = W4[(size_t)(kg * 4 + 1) * 128 + col];
  float4 w2 = W4[(size_t)(kg * 4 + 2) * 128 + col];
  float4 w3 = W4[(size_t)(kg * 4 + 3) * 128 + col];

  const float4* src = (const float4*)(partial + (size_t)b * NCH * MLPH);
  float4 p0 = src[t];
  float4 p1 = src[t + 256];
  float4 p2 = (t < 64) ? src[t + 512] : make_float4(0.f, 0.f, 0.f, 0.f);
  ((float4*)part)[t] = p0;
  ((float4*)part)[t + 256] = p1;
  if (t < 64) ((float4*)part)[t + 512] = p2;
  __syncthreads();
  if (t < 128) {
    float s = bf1[t];
#pragma unroll
    for (int c2 = 0; c2 < NCH; ++c2) s += part[c2 * MLPH + t];
    hid[t] = fmaxf(s, 0.f);
  }
  __syncthreads();

  float h0 = hid[kg * 4 + 0], h1 = hid[kg * 4 + 1];
  float h2 = hid[kg * 4 + 2], h3 = hid[kg * 4 + 3];
  float4 acc;
  acc.x = h0 * w0.x + h1 * w1.x + h2 * w2.x + h3 * w3.x;
  acc.y = h0 * w0.y + h1 * w1.y + h2 * w2.y + h3 * w3.y;
  acc.z = h0 * w0.z + h1 * w1.z + h2 * w2.z + h3 * w3.z;
  acc.w = h0 * w0.w + h1 * w1.w + h2 * w2.w + h3 * w3.w;
  *(float4*)&red[kg][oc * 4] = acc;
  __syncthreads();
  if (t < 32) {
    float s = bf2[q * 32 + t];
#pragma unroll
    for (int g = 0; g < 32; ++g) s += red[g][t];
    out[(size_t)b * NACT + q * 32 + t] = s;
  }
}

extern "C" void kernel_launch(void* const* d_in, const int* in_sizes, int n_in,
                              void* d_out, int out_size, void* d_ws, size_t ws_size,
                              hipStream_t stream) {
  const float* idx = (const float*)d_in[0];
  const float* x   = (const float*)d_in[1];
  const float* y   = (const float*)d_in[2];
  const float* adj = (const float*)d_in[3];
  const float* W1  = (const float*)d_in[4];
  const float* as1 = (const float*)d_in[5];
  const float* ad1 = (const float*)d_in[6];
  const float* b1  = (const float*)d_in[7];
  const float* W2  = (const float*)d_in[8];
  const float* as2 = (const float*)d_in[9];
  const float* ad2 = (const float*)d_in[10];
  const float* b2  = (const float*)d_in[11];
  const float* Wf1 = (const float*)d_in[12];
  const float* bf1 = (const float*)d_in[13];
  const float* Wf2 = (const float*)d_in[14];
  const float* bf2 = (const float*)d_in[15];
  float* out = (float*)d_out;

  uint8_t* ws = (uint8_t*)d_ws;
  uint32_t* maskT = (uint32_t*)ws;                       // 2 MB
  float* node2    = (float*)(ws + 2097152);              // 512 KB
  float* partial  = (float*)(ws + 2097152 + 524288);     // 576 KB

  hipLaunchKernelGGL(kfuse1, dim3(8, B_),   dim3(512), 0, stream,
                     adj, x, W1, as1, ad1, b1, W2, as2, maskT, node2);
  hipLaunchKernelGGL(kmid,   dim3(NCH, B_), dim3(256), 0, stream,
                     idx, y, node2, ad2, b2, maskT, Wf1, partial);
  hipLaunchKernelGGL(kmlp2w, dim3(16, B_),  dim3(256), 0, stream,
                     partial, bf1, Wf2, bf2, out);
}